// Round 3
// baseline (974.271 us; speedup 1.0000x reference)
//
#include <hip/hip_runtime.h>

typedef unsigned short u16;
typedef u16 u16x8 __attribute__((ext_vector_type(8)));
typedef u16 u16x4 __attribute__((ext_vector_type(4)));
typedef short s16x8 __attribute__((ext_vector_type(8)));
typedef float f32x4 __attribute__((ext_vector_type(4)));

__device__ __forceinline__ float b2f(u16 u) {
  unsigned int v = ((unsigned int)u) << 16;
  return __builtin_bit_cast(float, v);
}
__device__ __forceinline__ u16 f2b(float f) {
  unsigned int u = __builtin_bit_cast(unsigned int, f);
  u += 0x7FFFu + ((u >> 16) & 1u);
  return (u16)(u >> 16);
}

// ---------------- graph prep ----------------
__global__ void deg_kernel(const int* __restrict__ dst, int* __restrict__ deg, int E, int n) {
  int e = blockIdx.x * 256 + threadIdx.x;
  if (e < E) {
    int d = dst[e];
    d = min(max(d, 0), n - 1);
    atomicAdd(&deg[d], 1);
  }
}

__global__ void dis_kernel(const int* __restrict__ deg, float* __restrict__ dis, int n) {
  int i = blockIdx.x * 256 + threadIdx.x;
  if (i < n) dis[i] = 1.0f / sqrtf((float)(deg[i] + 1));  // +1 self-loop
}

// 3-phase exclusive scan of deg -> rowp
__global__ __launch_bounds__(256) void scanA(const int* __restrict__ cnt, int* __restrict__ bsum, int n) {
  __shared__ int s[256];
  int t = threadIdx.x, i = blockIdx.x * 256 + t;
  s[t] = (i < n) ? cnt[i] : 0;
  __syncthreads();
  for (int off = 128; off > 0; off >>= 1) {
    if (t < off) s[t] += s[t + off];
    __syncthreads();
  }
  if (t == 0) bsum[blockIdx.x] = s[0];
}

__global__ __launch_bounds__(256) void scanB(int* __restrict__ bsum, int nb) {
  __shared__ int s[256];
  int t = threadIdx.x;
  int v = (t < nb) ? bsum[t] : 0;
  s[t] = v;
  __syncthreads();
  for (int off = 1; off < 256; off <<= 1) {
    int x = (t >= off) ? s[t - off] : 0;
    __syncthreads();
    s[t] += x;
    __syncthreads();
  }
  if (t < nb) bsum[t] = s[t] - v;  // exclusive
}

__global__ __launch_bounds__(256) void scanC(const int* __restrict__ cnt, const int* __restrict__ bsum,
                                             int* __restrict__ rowp, int n) {
  __shared__ int s[256];
  int t = threadIdx.x, i = blockIdx.x * 256 + t;
  int v = (i < n) ? cnt[i] : 0;
  s[t] = v;
  __syncthreads();
  for (int off = 1; off < 256; off <<= 1) {
    int x = (t >= off) ? s[t - off] : 0;
    __syncthreads();
    s[t] += x;
    __syncthreads();
  }
  if (i < n) rowp[i + 1] = bsum[blockIdx.x] + s[t];
  if (i == 0) rowp[0] = 0;
}

__global__ void fill_kernel(const int* __restrict__ src, const int* __restrict__ dst,
                            const int* __restrict__ rowp, int* __restrict__ fill,
                            const float* __restrict__ dis, int* __restrict__ csr_s,
                            float* __restrict__ csr_w, int E, int n) {
  int e = blockIdx.x * 256 + threadIdx.x;
  if (e < E) {
    int s = src[e]; s = min(max(s, 0), n - 1);
    int d = dst[e]; d = min(max(d, 0), n - 1);
    int pos = rowp[d] + atomicAdd(&fill[d], 1);
    csr_s[pos] = s;
    csr_w[pos] = dis[s] * dis[d];
  }
}

// transpose + f32->bf16 convert: in [K,N] f32 row-major -> out [N,K] bf16
__global__ void transpose_cvt(const float* __restrict__ in, u16* __restrict__ out, int K, int N) {
  int idx = blockIdx.x * 256 + threadIdx.x;
  if (idx < K * N) {
    int k = idx / N, nn = idx - k * N;
    out[(size_t)nn * K + k] = f2b(in[idx]);
  }
}

// ---------------- LDS-free streaming MFMA GEMM ----------------
// C[M,N] = A[M,K] @ BT[N,K]^T (+bias). Requires N % 256 == 0, K % 64 == 0.
// Block = 4 waves = 64 rows x 256 cols; wave wv owns cols [wv*64, wv*64+64).
// MFMA A/B fragments are loaded DIRECTLY from global (per-lane 32B/16B contiguous
// runs -- same indices as the old LDS-tile read). No LDS, no barriers: waves are
// fully independent, loads from the next k-step stay in flight under the MFMAs of
// the current one (2-half-step register ping-pong). The 4 waves of a block read
// identical A addresses -> dedup in L1/L2, so A streams from HBM exactly once
// (grid.x covers full N). B (<=512KB) is L2-resident.
template <bool A_F32, bool OUT_F32>
__global__ __launch_bounds__(256) void gemm_stream(const void* __restrict__ Ap,
                                                   const u16* __restrict__ BT,
                                                   const float* __restrict__ bias,
                                                   void* __restrict__ Cp, int M, int N, int K) {
  const int tid = threadIdx.x;
  const int lane = tid & 63;
  const int wv = tid >> 6;
  const int l = lane & 15, q = lane >> 4;
  const int m0 = blockIdx.y * 64;
  const int n0 = blockIdx.x * 256 + wv * 64;

  // per-lane fragment base pointers (rows clamped; stores are guarded)
  const float* afp[4];
  const u16*   abp[4];
  const u16*   bbp[4];
#pragma unroll
  for (int mi = 0; mi < 4; mi++) {
    int r = m0 + mi * 16 + l;
    if (r > M - 1) r = M - 1;
    if (A_F32) afp[mi] = (const float*)Ap + (size_t)r * K + q * 8;
    else       abp[mi] = (const u16*)Ap + (size_t)r * K + q * 8;
  }
#pragma unroll
  for (int ni = 0; ni < 4; ni++) {
    int c = n0 + ni * 16 + l;
    bbp[ni] = BT + (size_t)c * K + q * 8;
  }

  f32x4 acc[4][4] = {};
  float4 arA[4][2], arB[4][2];   // f32-A raw staging (two sets)
  u16x8 abA[4], abB[4];          // bf16-A staging (two sets)
  u16x8 brA[4], brB[4];          // B staging (two sets)
  s16x8 af[4];

  auto loadA = [&](float4 (&ar)[4][2], u16x8 (&ab)[4], int kt) {
    if (A_F32) {
#pragma unroll
      for (int mi = 0; mi < 4; mi++) {
        ar[mi][0] = *(const float4*)(afp[mi] + kt);
        ar[mi][1] = *(const float4*)(afp[mi] + kt + 4);
      }
    } else {
#pragma unroll
      for (int mi = 0; mi < 4; mi++) ab[mi] = *(const u16x8*)(abp[mi] + kt);
    }
  };
  auto loadB = [&](u16x8 (&br)[4], int kt) {
#pragma unroll
    for (int ni = 0; ni < 4; ni++) br[ni] = *(const u16x8*)(bbp[ni] + kt);
  };
  auto cvtA = [&](float4 (&ar)[4][2], u16x8 (&ab)[4]) {
    if (A_F32) {
#pragma unroll
      for (int mi = 0; mi < 4; mi++) {
        unsigned int d0, d1, d2, d3;
        asm("v_cvt_pk_bf16_f32 %0, %1, %2" : "=v"(d0) : "v"(ar[mi][0].x), "v"(ar[mi][0].y));
        asm("v_cvt_pk_bf16_f32 %0, %1, %2" : "=v"(d1) : "v"(ar[mi][0].z), "v"(ar[mi][0].w));
        asm("v_cvt_pk_bf16_f32 %0, %1, %2" : "=v"(d2) : "v"(ar[mi][1].x), "v"(ar[mi][1].y));
        asm("v_cvt_pk_bf16_f32 %0, %1, %2" : "=v"(d3) : "v"(ar[mi][1].z), "v"(ar[mi][1].w));
        int4 di; di.x = d0; di.y = d1; di.z = d2; di.w = d3;
        af[mi] = __builtin_bit_cast(s16x8, di);
      }
    } else {
#pragma unroll
      for (int mi = 0; mi < 4; mi++) af[mi] = __builtin_bit_cast(s16x8, ab[mi]);
    }
  };
  auto domfma = [&](u16x8 (&br)[4]) {
#pragma unroll
    for (int mi = 0; mi < 4; mi++)
#pragma unroll
      for (int ni = 0; ni < 4; ni++)
        acc[mi][ni] = __builtin_amdgcn_mfma_f32_16x16x32_bf16(
            af[mi], __builtin_bit_cast(s16x8, br[ni]), acc[mi][ni], 0, 0, 0);
  };

  loadA(arA, abA, 0);
  loadB(brA, 0);
  for (int kt = 0; kt < K; kt += 64) {
    if (kt + 32 < K) { loadA(arB, abB, kt + 32); loadB(brB, kt + 32); }
    cvtA(arA, abA);
    domfma(brA);
    if (kt + 64 < K) { loadA(arA, abA, kt + 64); loadB(brA, kt + 64); }
    cvtA(arB, abB);
    domfma(brB);
  }

#pragma unroll
  for (int ni = 0; ni < 4; ni++) {
    int col = n0 + ni * 16 + l;
    float bv = bias ? bias[col] : 0.f;
#pragma unroll
    for (int mi = 0; mi < 4; mi++) {
#pragma unroll
      for (int j = 0; j < 4; j++) {
        int row = m0 + mi * 16 + q * 4 + j;
        if (row < M) {
          float v = acc[mi][ni][j] + bv;
          if (OUT_F32)
            ((float*)Cp)[(size_t)row * N + col] = v;
          else
            ((u16*)Cp)[(size_t)row * N + col] = f2b(v);
        }
      }
    }
  }
}

// ---------------- CSR aggregation over 256 bf16 features, one wave per node ----------------
// Edge loop unrolled 4x: issue 4 independent index loads, then 4 independent 512B
// gathers, then FMAs — breaks the serial load->gather->fma chain.
template <bool RELU>
__global__ __launch_bounds__(256) void agg_kernel(const u16* __restrict__ tab,
                                                  const int* __restrict__ rowp,
                                                  const int* __restrict__ csr_s,
                                                  const float* __restrict__ csr_w,
                                                  const float* __restrict__ dis,
                                                  const float* __restrict__ bias,
                                                  u16* __restrict__ out, int n) {
  int wv = threadIdx.x >> 6, lane = threadIdx.x & 63;
  int node = blockIdx.x * 4 + wv;
  if (node >= n) return;
  int f0 = lane * 4;
  float sw = dis[node];
  sw *= sw;  // self-loop weight = 1/deg
  u16x4 v = *(const u16x4*)&tab[(size_t)node * 256 + f0];
  float a0 = sw * b2f(v[0]), a1 = sw * b2f(v[1]), a2 = sw * b2f(v[2]), a3 = sw * b2f(v[3]);
  int e0 = rowp[node], e1 = rowp[node + 1];
  int e = e0;
  for (; e + 4 <= e1; e += 4) {
    int s0 = csr_s[e], s1 = csr_s[e + 1], s2 = csr_s[e + 2], s3 = csr_s[e + 3];
    float w0 = csr_w[e], w1 = csr_w[e + 1], w2 = csr_w[e + 2], w3 = csr_w[e + 3];
    u16x4 u0 = *(const u16x4*)&tab[(size_t)s0 * 256 + f0];
    u16x4 u1 = *(const u16x4*)&tab[(size_t)s1 * 256 + f0];
    u16x4 u2 = *(const u16x4*)&tab[(size_t)s2 * 256 + f0];
    u16x4 u3 = *(const u16x4*)&tab[(size_t)s3 * 256 + f0];
    a0 += w0 * b2f(u0[0]) + w1 * b2f(u1[0]) + w2 * b2f(u2[0]) + w3 * b2f(u3[0]);
    a1 += w0 * b2f(u0[1]) + w1 * b2f(u1[1]) + w2 * b2f(u2[1]) + w3 * b2f(u3[1]);
    a2 += w0 * b2f(u0[2]) + w1 * b2f(u1[2]) + w2 * b2f(u2[2]) + w3 * b2f(u3[2]);
    a3 += w0 * b2f(u0[3]) + w1 * b2f(u1[3]) + w2 * b2f(u2[3]) + w3 * b2f(u3[3]);
  }
  for (; e < e1; e++) {
    int s = csr_s[e];
    float w = csr_w[e];
    u16x4 u = *(const u16x4*)&tab[(size_t)s * 256 + f0];
    a0 += w * b2f(u[0]);
    a1 += w * b2f(u[1]);
    a2 += w * b2f(u[2]);
    a3 += w * b2f(u[3]);
  }
  if (RELU) {
    a0 = fmaxf(a0 + bias[f0 + 0], 0.f);
    a1 = fmaxf(a1 + bias[f0 + 1], 0.f);
    a2 = fmaxf(a2 + bias[f0 + 2], 0.f);
    a3 = fmaxf(a3 + bias[f0 + 3], 0.f);
  }
  u16x4 o;
  o[0] = f2b(a0); o[1] = f2b(a1); o[2] = f2b(a2); o[3] = f2b(a3);
  *(u16x4*)&out[(size_t)node * 256 + f0] = o;
}

extern "C" void kernel_launch(void* const* d_in, const int* in_sizes, int n_in,
                              void* d_out, int out_size, void* d_ws, size_t ws_size,
                              hipStream_t stream) {
  const float* x  = (const float*)d_in[0];
  const int*   ei = (const int*)d_in[1];
  const float* W1 = (const float*)d_in[2];
  const float* b1 = (const float*)d_in[3];
  const float* W2 = (const float*)d_in[4];
  const float* b2 = (const float*)d_in[5];

  const int MID = in_sizes[3];            // 256
  const int IN  = in_sizes[5];            // 1024
  const int n   = in_sizes[0] / IN;       // 50000
  const int E   = in_sizes[1] / 2;        // 1600000
  const int* srcv = ei;
  const int* dstv = ei + E;

  char* w = (char*)d_ws;
  size_t off = 0;
  auto alloc = [&](size_t bytes) -> void* {
    void* p = w + off;
    off += (bytes + 255) & ~(size_t)255;
    return p;
  };
  int*   deg   = (int*)alloc((size_t)n * 4);
  int*   rowp  = (int*)alloc((size_t)(n + 1) * 4);
  int*   fill  = (int*)alloc((size_t)n * 4);
  int*   bsum  = (int*)alloc(1024);
  int*   csr_s = (int*)alloc((size_t)E * 4);
  float* csr_w = (float*)alloc((size_t)E * 4);
  float* dis   = (float*)alloc((size_t)n * 4);
  u16*   W1T   = (u16*)alloc((size_t)IN * MID * 2);
  u16*   W2T   = (u16*)alloc((size_t)IN * MID * 2);
  u16*   xw    = (u16*)alloc((size_t)n * MID * 2);
  u16*   h     = (u16*)alloc((size_t)n * MID * 2);
  u16*   ah    = xw;  // xw dead after agg1; reuse for agg2 output

  hipMemsetAsync(deg, 0, (size_t)n * 4, stream);
  hipMemsetAsync(fill, 0, (size_t)n * 4, stream);

  transpose_cvt<<<(IN * MID + 255) / 256, 256, 0, stream>>>(W1, W1T, IN, MID);
  transpose_cvt<<<(IN * MID + 255) / 256, 256, 0, stream>>>(W2, W2T, MID, IN);

  const int nb = (n + 255) / 256;  // 196 <= 256
  deg_kernel<<<(E + 255) / 256, 256, 0, stream>>>(dstv, deg, E, n);
  dis_kernel<<<nb, 256, 0, stream>>>(deg, dis, n);
  scanA<<<nb, 256, 0, stream>>>(deg, bsum, n);
  scanB<<<1, 256, 0, stream>>>(bsum, nb);
  scanC<<<nb, 256, 0, stream>>>(deg, bsum, rowp, n);
  fill_kernel<<<(E + 255) / 256, 256, 0, stream>>>(srcv, dstv, rowp, fill, dis, csr_s, csr_w, E, n);

  // xw = bf16(x) @ W1   [n, MID] bf16
  dim3 g1(MID / 256, (n + 63) / 64);
  gemm_stream<true, false><<<g1, 256, 0, stream>>>(x, W1T, nullptr, xw, n, MID, IN);
  // h = relu(A @ xw + b1)   bf16
  agg_kernel<true><<<(n + 3) / 4, 256, 0, stream>>>(xw, rowp, csr_s, csr_w, dis, b1, h, n);
  // ah = A @ h   bf16
  agg_kernel<false><<<(n + 3) / 4, 256, 0, stream>>>(h, rowp, csr_s, csr_w, dis, nullptr, ah, n);
  // out = ah @ W2 + b2   [n, IN] f32
  dim3 g2(IN / 256, (n + 63) / 64);
  gemm_stream<false, true><<<g2, 256, 0, stream>>>(ah, W2T, b2, d_out, n, IN, MID);
}

// Round 4
// 891.157 us; speedup vs baseline: 1.0933x; 1.0933x over previous
//
#include <hip/hip_runtime.h>

typedef unsigned short u16;
typedef u16 u16x8 __attribute__((ext_vector_type(8)));
typedef u16 u16x4 __attribute__((ext_vector_type(4)));
typedef short s16x8 __attribute__((ext_vector_type(8)));
typedef float f32x4 __attribute__((ext_vector_type(4)));

__device__ __forceinline__ float b2f(u16 u) {
  unsigned int v = ((unsigned int)u) << 16;
  return __builtin_bit_cast(float, v);
}
__device__ __forceinline__ u16 f2b(float f) {
  unsigned int u = __builtin_bit_cast(unsigned int, f);
  u += 0x7FFFu + ((u >> 16) & 1u);
  return (u16)(u >> 16);
}

// async global->LDS, 16B per lane. LDS dest must be wave-uniform-base + lane*16.
__device__ __forceinline__ void gld16(void* lds, const void* g) {
  __builtin_amdgcn_global_load_lds(
      (const __attribute__((address_space(1))) void*)g,
      (__attribute__((address_space(3))) void*)lds, 16, 0, 0);
}

// ---------------- graph prep ----------------
__global__ void deg_kernel(const int* __restrict__ dst, int* __restrict__ deg, int E, int n) {
  int e = blockIdx.x * 256 + threadIdx.x;
  if (e < E) {
    int d = dst[e];
    d = min(max(d, 0), n - 1);
    atomicAdd(&deg[d], 1);
  }
}

__global__ void dis_kernel(const int* __restrict__ deg, float* __restrict__ dis, int n) {
  int i = blockIdx.x * 256 + threadIdx.x;
  if (i < n) dis[i] = 1.0f / sqrtf((float)(deg[i] + 1));  // +1 self-loop
}

// 3-phase exclusive scan of deg -> rowp
__global__ __launch_bounds__(256) void scanA(const int* __restrict__ cnt, int* __restrict__ bsum, int n) {
  __shared__ int s[256];
  int t = threadIdx.x, i = blockIdx.x * 256 + t;
  s[t] = (i < n) ? cnt[i] : 0;
  __syncthreads();
  for (int off = 128; off > 0; off >>= 1) {
    if (t < off) s[t] += s[t + off];
    __syncthreads();
  }
  if (t == 0) bsum[blockIdx.x] = s[0];
}

__global__ __launch_bounds__(256) void scanB(int* __restrict__ bsum, int nb) {
  __shared__ int s[256];
  int t = threadIdx.x;
  int v = (t < nb) ? bsum[t] : 0;
  s[t] = v;
  __syncthreads();
  for (int off = 1; off < 256; off <<= 1) {
    int x = (t >= off) ? s[t - off] : 0;
    __syncthreads();
    s[t] += x;
    __syncthreads();
  }
  if (t < nb) bsum[t] = s[t] - v;  // exclusive
}

__global__ __launch_bounds__(256) void scanC(const int* __restrict__ cnt, const int* __restrict__ bsum,
                                             int* __restrict__ rowp, int n) {
  __shared__ int s[256];
  int t = threadIdx.x, i = blockIdx.x * 256 + t;
  int v = (i < n) ? cnt[i] : 0;
  s[t] = v;
  __syncthreads();
  for (int off = 1; off < 256; off <<= 1) {
    int x = (t >= off) ? s[t - off] : 0;
    __syncthreads();
    s[t] += x;
    __syncthreads();
  }
  if (i < n) rowp[i + 1] = bsum[blockIdx.x] + s[t];
  if (i == 0) rowp[0] = 0;
}

__global__ void fill_kernel(const int* __restrict__ src, const int* __restrict__ dst,
                            const int* __restrict__ rowp, int* __restrict__ fill,
                            const float* __restrict__ dis, int* __restrict__ csr_s,
                            float* __restrict__ csr_w, int E, int n) {
  int e = blockIdx.x * 256 + threadIdx.x;
  if (e < E) {
    int s = src[e]; s = min(max(s, 0), n - 1);
    int d = dst[e]; d = min(max(d, 0), n - 1);
    int pos = rowp[d] + atomicAdd(&fill[d], 1);
    csr_s[pos] = s;
    csr_w[pos] = dis[s] * dis[d];
  }
}

// transpose + f32->bf16 convert: in [K,N] f32 row-major -> out [N,K] bf16
__global__ void transpose_cvt(const float* __restrict__ in, u16* __restrict__ out, int K, int N) {
  int idx = blockIdx.x * 256 + threadIdx.x;
  if (idx < K * N) {
    int k = idx / N, nn = idx - k * N;
    out[(size_t)nn * K + k] = f2b(in[idx]);
  }
}

// ---------------- m97-style MFMA GEMM: C[M,N] = A[M,K] @ BT[N,K]^T (+bias) ----------------
// 128x128 tile, 4 waves each 64x64 (4x4 of 16x16x32 mfma), BK=32, single LDS buffer,
// 2 barriers/iter, global_load_lds(width=16) staging (m97 config: 874 TF at 4096^3;
// reg-staged variant of the same loop = 646 TF, m151).
// A_F32: A staged raw f32 (16KB tile), converted to bf16 AFTER ds_read via cvt_pk.
// LDS is linear (global_load_lds requirement); bank conflicts fixed by pre-swizzling
// the per-lane GLOBAL source and applying the same XOR on the ds_read address
// (rule #21: both-sides-or-neither). f32 rows (128B): byte ^= (row&7)<<4 -> 2-way (free).
// bf16 rows (64B): byte ^= (row&3)<<4 -> 4-way residual (1.58x, acceptable).
template <bool A_F32, bool OUT_F32>
__global__ __launch_bounds__(256) void gemm_m97(const void* __restrict__ Ap,
                                                const u16* __restrict__ BT,
                                                const float* __restrict__ bias,
                                                void* __restrict__ Cp, int M, int N, int K) {
  constexpr int ABYTES = A_F32 ? 16384 : 8192;  // 128 rows x 32 cols x (4|2) B
  __shared__ alignas(16) unsigned char smem[ABYTES + 8192];
  unsigned char* Asm = smem;
  unsigned char* Bsm = smem + ABYTES;

  const int tid = threadIdx.x;
  const int m0 = blockIdx.y * 128, n0 = blockIdx.x * 128;
  const int lane = tid & 63, wv = tid >> 6;
  const int wr = (wv >> 1) * 64, wc = (wv & 1) * 64;
  const int q = lane >> 4, l = lane & 15;
  f32x4 acc[4][4] = {};

  // Per-chunk global source base pointers (pre-swizzled); add kt*elt_bytes per iter.
  constexpr int NA = A_F32 ? 4 : 2;
  constexpr size_t AB = A_F32 ? 4 : 2;
  const char* a_src[NA];
  const char* b_src[2];
#pragma unroll
  for (int i = 0; i < NA; i++) {
    int c = tid + i * 256;
    int r, lb;
    if (A_F32) {
      r = c >> 3;                       // 8 chunks of 16B per 128B row
      int sb = (c & 7) * 16;            // physical in-row byte
      lb = sb ^ ((r & 7) << 4);         // logical in-row byte (swizzle inverse)
    } else {
      r = c >> 2;                       // 4 chunks of 16B per 64B row
      int sb = (c & 3) * 16;
      lb = sb ^ ((r & 3) << 4);
    }
    int gr = m0 + r;
    if (gr > M - 1) gr = M - 1;         // clamp; garbage rows are discarded at store
    a_src[i] = (const char*)Ap + (size_t)gr * K * AB + lb;
  }
#pragma unroll
  for (int i = 0; i < 2; i++) {
    int c = tid + i * 256;
    int r = c >> 2;
    int sb = (c & 3) * 16;
    int lb = sb ^ ((r & 3) << 4);
    b_src[i] = (const char*)BT + (size_t)(n0 + r) * K * 2 + lb;
  }

  for (int kt = 0; kt < K; kt += 32) {
    // ---- stage: async direct-to-LDS, linear dest (base + lane*16 per wave) ----
#pragma unroll
    for (int i = 0; i < NA; i++)
      gld16(Asm + (tid + i * 256) * 16, a_src[i] + (size_t)kt * AB);
#pragma unroll
    for (int i = 0; i < 2; i++)
      gld16(Bsm + (tid + i * 256) * 16, b_src[i] + (size_t)kt * 2);
    __syncthreads();  // drains vmcnt(0): LDS writes complete for all waves

    // ---- fragments (swizzled read) ----
    s16x8 af[4], bf[4];
    if (A_F32) {
#pragma unroll
      for (int mi = 0; mi < 4; mi++) {
        int R = wr + mi * 16 + l;
        int xr = (R & 7) << 4;
        const char* rb = (const char*)Asm + R * 128;
        float4 lo = *(const float4*)(rb + ((q * 32) ^ xr));
        float4 hi = *(const float4*)(rb + ((q * 32 + 16) ^ xr));
        unsigned int d0, d1, d2, d3;
        asm("v_cvt_pk_bf16_f32 %0, %1, %2" : "=v"(d0) : "v"(lo.x), "v"(lo.y));
        asm("v_cvt_pk_bf16_f32 %0, %1, %2" : "=v"(d1) : "v"(lo.z), "v"(lo.w));
        asm("v_cvt_pk_bf16_f32 %0, %1, %2" : "=v"(d2) : "v"(hi.x), "v"(hi.y));
        asm("v_cvt_pk_bf16_f32 %0, %1, %2" : "=v"(d3) : "v"(hi.z), "v"(hi.w));
        int4 di;
        di.x = (int)d0; di.y = (int)d1; di.z = (int)d2; di.w = (int)d3;
        af[mi] = __builtin_bit_cast(s16x8, di);
      }
    } else {
#pragma unroll
      for (int mi = 0; mi < 4; mi++) {
        int R = wr + mi * 16 + l;
        af[mi] = *(const s16x8*)((const char*)Asm + R * 64 + ((q * 16) ^ ((R & 3) << 4)));
      }
    }
#pragma unroll
    for (int ni = 0; ni < 4; ni++) {
      int C = wc + ni * 16 + l;
      bf[ni] = *(const s16x8*)((const char*)Bsm + C * 64 + ((q * 16) ^ ((C & 3) << 4)));
    }

#pragma unroll
    for (int mi = 0; mi < 4; mi++)
#pragma unroll
      for (int ni = 0; ni < 4; ni++)
        acc[mi][ni] = __builtin_amdgcn_mfma_f32_16x16x32_bf16(af[mi], bf[ni], acc[mi][ni], 0, 0, 0);
    __syncthreads();  // protect LDS before next iter's staging
  }

#pragma unroll
  for (int ni = 0; ni < 4; ni++) {
    int col = n0 + wc + ni * 16 + l;
    float bv = bias ? bias[col] : 0.f;
#pragma unroll
    for (int mi = 0; mi < 4; mi++) {
#pragma unroll
      for (int j = 0; j < 4; j++) {
        int row = m0 + wr + mi * 16 + q * 4 + j;
        if (row < M) {
          float v = acc[mi][ni][j] + bv;
          if (OUT_F32)
            ((float*)Cp)[(size_t)row * N + col] = v;
          else
            ((u16*)Cp)[(size_t)row * N + col] = f2b(v);
        }
      }
    }
  }
}

// ---------------- CSR aggregation over 256 bf16 features, one wave per node ----------------
// Edge loop unrolled 4x: issue 4 independent index loads, then 4 independent 512B
// gathers, then FMAs — breaks the serial load->gather->fma chain.
template <bool RELU>
__global__ __launch_bounds__(256) void agg_kernel(const u16* __restrict__ tab,
                                                  const int* __restrict__ rowp,
                                                  const int* __restrict__ csr_s,
                                                  const float* __restrict__ csr_w,
                                                  const float* __restrict__ dis,
                                                  const float* __restrict__ bias,
                                                  u16* __restrict__ out, int n) {
  int wv = threadIdx.x >> 6, lane = threadIdx.x & 63;
  int node = blockIdx.x * 4 + wv;
  if (node >= n) return;
  int f0 = lane * 4;
  float sw = dis[node];
  sw *= sw;  // self-loop weight = 1/deg
  u16x4 v = *(const u16x4*)&tab[(size_t)node * 256 + f0];
  float a0 = sw * b2f(v[0]), a1 = sw * b2f(v[1]), a2 = sw * b2f(v[2]), a3 = sw * b2f(v[3]);
  int e0 = rowp[node], e1 = rowp[node + 1];
  int e = e0;
  for (; e + 4 <= e1; e += 4) {
    int s0 = csr_s[e], s1 = csr_s[e + 1], s2 = csr_s[e + 2], s3 = csr_s[e + 3];
    float w0 = csr_w[e], w1 = csr_w[e + 1], w2 = csr_w[e + 2], w3 = csr_w[e + 3];
    u16x4 u0 = *(const u16x4*)&tab[(size_t)s0 * 256 + f0];
    u16x4 u1 = *(const u16x4*)&tab[(size_t)s1 * 256 + f0];
    u16x4 u2 = *(const u16x4*)&tab[(size_t)s2 * 256 + f0];
    u16x4 u3 = *(const u16x4*)&tab[(size_t)s3 * 256 + f0];
    a0 += w0 * b2f(u0[0]) + w1 * b2f(u1[0]) + w2 * b2f(u2[0]) + w3 * b2f(u3[0]);
    a1 += w0 * b2f(u0[1]) + w1 * b2f(u1[1]) + w2 * b2f(u2[1]) + w3 * b2f(u3[1]);
    a2 += w0 * b2f(u0[2]) + w1 * b2f(u1[2]) + w2 * b2f(u2[2]) + w3 * b2f(u3[2]);
    a3 += w0 * b2f(u0[3]) + w1 * b2f(u1[3]) + w2 * b2f(u2[3]) + w3 * b2f(u3[3]);
  }
  for (; e < e1; e++) {
    int s = csr_s[e];
    float w = csr_w[e];
    u16x4 u = *(const u16x4*)&tab[(size_t)s * 256 + f0];
    a0 += w * b2f(u[0]);
    a1 += w * b2f(u[1]);
    a2 += w * b2f(u[2]);
    a3 += w * b2f(u[3]);
  }
  if (RELU) {
    a0 = fmaxf(a0 + bias[f0 + 0], 0.f);
    a1 = fmaxf(a1 + bias[f0 + 1], 0.f);
    a2 = fmaxf(a2 + bias[f0 + 2], 0.f);
    a3 = fmaxf(a3 + bias[f0 + 3], 0.f);
  }
  u16x4 o;
  o[0] = f2b(a0); o[1] = f2b(a1); o[2] = f2b(a2); o[3] = f2b(a3);
  *(u16x4*)&out[(size_t)node * 256 + f0] = o;
}

extern "C" void kernel_launch(void* const* d_in, const int* in_sizes, int n_in,
                              void* d_out, int out_size, void* d_ws, size_t ws_size,
                              hipStream_t stream) {
  const float* x  = (const float*)d_in[0];
  const int*   ei = (const int*)d_in[1];
  const float* W1 = (const float*)d_in[2];
  const float* b1 = (const float*)d_in[3];
  const float* W2 = (const float*)d_in[4];
  const float* b2 = (const float*)d_in[5];

  const int MID = in_sizes[3];            // 256
  const int IN  = in_sizes[5];            // 1024
  const int n   = in_sizes[0] / IN;       // 50000
  const int E   = in_sizes[1] / 2;        // 1600000
  const int* srcv = ei;
  const int* dstv = ei + E;

  char* w = (char*)d_ws;
  size_t off = 0;
  auto alloc = [&](size_t bytes) -> void* {
    void* p = w + off;
    off += (bytes + 255) & ~(size_t)255;
    return p;
  };
  int*   deg   = (int*)alloc((size_t)n * 4);
  int*   rowp  = (int*)alloc((size_t)(n + 1) * 4);
  int*   fill  = (int*)alloc((size_t)n * 4);
  int*   bsum  = (int*)alloc(1024);
  int*   csr_s = (int*)alloc((size_t)E * 4);
  float* csr_w = (float*)alloc((size_t)E * 4);
  float* dis   = (float*)alloc((size_t)n * 4);
  u16*   W1T   = (u16*)alloc((size_t)IN * MID * 2);
  u16*   W2T   = (u16*)alloc((size_t)IN * MID * 2);
  u16*   xw    = (u16*)alloc((size_t)n * MID * 2);
  u16*   h     = (u16*)alloc((size_t)n * MID * 2);
  u16*   ah    = xw;  // xw dead after agg1; reuse for agg2 output

  hipMemsetAsync(deg, 0, (size_t)n * 4, stream);
  hipMemsetAsync(fill, 0, (size_t)n * 4, stream);

  transpose_cvt<<<(IN * MID + 255) / 256, 256, 0, stream>>>(W1, W1T, IN, MID);
  transpose_cvt<<<(IN * MID + 255) / 256, 256, 0, stream>>>(W2, W2T, MID, IN);

  const int nb = (n + 255) / 256;  // 196 <= 256
  deg_kernel<<<(E + 255) / 256, 256, 0, stream>>>(dstv, deg, E, n);
  dis_kernel<<<nb, 256, 0, stream>>>(deg, dis, n);
  scanA<<<nb, 256, 0, stream>>>(deg, bsum, n);
  scanB<<<1, 256, 0, stream>>>(bsum, nb);
  scanC<<<nb, 256, 0, stream>>>(deg, bsum, rowp, n);
  fill_kernel<<<(E + 255) / 256, 256, 0, stream>>>(srcv, dstv, rowp, fill, dis, csr_s, csr_w, E, n);

  // xw = bf16(x) @ W1   [n, MID] bf16
  dim3 g1(MID / 128, (n + 127) / 128);
  gemm_m97<true, false><<<g1, 256, 0, stream>>>(x, W1T, nullptr, xw, n, MID, IN);
  // h = relu(A @ xw + b1)   bf16
  agg_kernel<true><<<(n + 3) / 4, 256, 0, stream>>>(xw, rowp, csr_s, csr_w, dis, b1, h, n);
  // ah = A @ h   bf16
  agg_kernel<false><<<(n + 3) / 4, 256, 0, stream>>>(h, rowp, csr_s, csr_w, dis, nullptr, ah, n);
  // out = ah @ W2 + b2   [n, IN] f32
  dim3 g2(IN / 128, (n + 127) / 128);
  gemm_m97<false, true><<<g2, 256, 0, stream>>>(ah, W2T, b2, d_out, n, IN, MID);
}